// Round 13
// baseline (34.468 us; speedup 1.0000x reference)
//
#include <hip/hip_runtime.h>
#include <hip/hip_bf16.h>

#define NA 3
#define NT 32
#define NC 4
#define NR 8
#define NK 1024
#define NPIX 4096            // 64*64
#define NOUT (NT * NC * NK)  // 131072 complex outputs
#define NRK (NR * NK)        // 8192 (r,k) pairs
#define ROWB 144             // LDS row pitch: 64 bf16 + 8 pad (bank-balanced)
#define CHB (16 * ROWB)      // per-channel LDS block (16 i-rows)

typedef __attribute__((ext_vector_type(8))) short bf16x8;
typedef __attribute__((ext_vector_type(4))) float f32x4;

static __device__ __forceinline__ short f2bf(float f) {
    union { __hip_bfloat16 h; short s; } u;
    u.h = __float2bfloat16(f);
    return u.s;
}

// ---------------------------------------------------------------------------
// detect16: 16 blocks, each scans 1024 floats of candA; flag16[b]=1 if any
// |v| > pi.  candA==mps (N(0,1)) -> OR over all 16 slots is 1 w.p. 1-2e-12;
// candA==trj (uniform in (-pi,pi)) -> all 0.  [semantics proven r7-r12]
// ---------------------------------------------------------------------------
__global__ __launch_bounds__(256) void detect16(const float* __restrict__ A,
                                                int* __restrict__ flag16) {
    __shared__ int s;
    if (threadIdx.x == 0) s = 0;
    __syncthreads();
    const float4 v = ((const float4*)A)[blockIdx.x * 256 + threadIdx.x];
    if (fabsf(v.x) > 3.1416f || fabsf(v.y) > 3.1416f ||
        fabsf(v.z) > 3.1416f || fabsf(v.w) > 3.1416f)
        atomicOr(&s, 1);
    __syncthreads();
    if (threadIdx.x == 0) flag16[blockIdx.x] = s;
}

// ---------------------------------------------------------------------------
// nudft_fused: separable NUDFT + fused combine epilogue.
// Block = 16 rk (rk0 = bx*16, all same r = bx>>6, k0 = (bx&63)*16).
// 4 waves x 3 channels each; all 64 i-rows walked in 4 staged LDS slices.
//   stage1 (MFMA): G[i_off,16rk] = sum_j s'[ch,i,j]*Ex[j,rk]   (K=64, 2 MFMA)
//   stage2 (VALU): y[ch,rk] += Ey[i,rk]*G  (f32)
// Lane rule (A/B identical k-slots -> HW-permutation invariant, r11/r12):
//   j = h*32 + g*8 + e, g = lane>>4; C row = g*4+reg (m89-verified).
// Epilogue: y -> LDS [12][16], then out[t,c,k] = dcf[r,k]*sum_a phi[a,t]*y
// for every t with sidx[t]==r, planar f32 out (proven r7-r12).
// ---------------------------------------------------------------------------
__global__ __launch_bounds__(256, 2) void nudft_fused(
    const float* __restrict__ x,
    const float* __restrict__ candA,
    const float* __restrict__ candB,
    const int*  __restrict__ flag16,
    const float* __restrict__ phi,
    const float* __restrict__ dcf,
    const int*  __restrict__ sidx,
    float* __restrict__ out)
{
    __shared__ char slds[12 * CHB];     // 27648 B
    __shared__ float2 ylds[12][16];     // 1536 B

    int fl = 0;
#pragma unroll
    for (int i = 0; i < 16; ++i) fl |= flag16[i];
    const float* __restrict__ trj = fl ? candB : candA;
    const float* __restrict__ mps = fl ? candA : candB;

    const int tid = threadIdx.x;
    const int w   = tid >> 6;
    const int l   = tid & 63;
    const int col = l & 15;
    const int g   = l >> 4;

    const int rk0 = blockIdx.x * 16;
    const int r   = rk0 >> 10;
    const int k0  = rk0 & (NK - 1);
    const int k   = k0 + col;

    const float t0 = trj[(r * 2 + 0) * NK + k];
    const float t1 = trj[(r * 2 + 1) * NK + k];

    // ---- B fragments: Ex[j = h*32 + g*8 + e], materialized once ----
    bf16x8 breh[2], bimh[2];
    {
        float pr[8], pi[8];
        float sr, cr; __sincosf(t1, &sr, &cr);
        float s0, c0; __sincosf(t1 * (float)(g * 8 - 32), &s0, &c0);
        pr[0] = c0; pi[0] = -s0;
#pragma unroll
        for (int e = 1; e < 8; ++e) {
            const float nr = pr[e-1] * cr + pi[e-1] * sr;
            const float ni = pi[e-1] * cr - pr[e-1] * sr;
            pr[e] = nr; pi[e] = ni;
        }
        union { bf16x8 v; short s[8]; } u0, u1;
#pragma unroll
        for (int e = 0; e < 8; ++e) { u0.s[e] = f2bf(pr[e]); u1.s[e] = f2bf(pi[e]); }
        breh[0] = u0.v; bimh[0] = u1.v;
        float s32, c32; __sincosf(32.f * t1, &s32, &c32);
#pragma unroll
        for (int e = 0; e < 8; ++e) {
            const float nr = pr[e] * c32 + pi[e] * s32;
            const float ni = pi[e] * c32 - pr[e] * s32;
            u0.s[e] = f2bf(nr); u1.s[e] = f2bf(ni);
        }
        breh[1] = u0.v; bimh[1] = u1.v;
    }

    float yre[3] = {0.f, 0.f, 0.f}, yim[3] = {0.f, 0.f, 0.f};

#pragma unroll
    for (int sl = 0; sl < 4; ++sl) {
        const int i0 = sl * 16;
        if (sl) __syncthreads();
        // ---- stage s'[12ch][16i][64j] bf16, pitch-144 rows ----
        if (tid < 192) {
            const int ch = tid >> 4, ii = tid & 15;
            const int a = ch >> 2, c = ch & 3;
            const float* __restrict__ xr = x   + a * NPIX + (i0 + ii) * 64;
            const float* __restrict__ mr = mps + c * NPIX + (i0 + ii) * 64;
            char* dst = slds + ch * CHB + ii * ROWB;
#pragma unroll
            for (int o = 0; o < 8; ++o) {
                const float4 xv0 = *(const float4*)(xr + o * 8);
                const float4 xv1 = *(const float4*)(xr + o * 8 + 4);
                const float4 mv0 = *(const float4*)(mr + o * 8);
                const float4 mv1 = *(const float4*)(mr + o * 8 + 4);
                union { bf16x8 v; short s[8]; } pk;
                pk.s[0] = f2bf(xv0.x * mv0.x); pk.s[1] = f2bf(xv0.y * mv0.y);
                pk.s[2] = f2bf(xv0.z * mv0.z); pk.s[3] = f2bf(xv0.w * mv0.w);
                pk.s[4] = f2bf(xv1.x * mv1.x); pk.s[5] = f2bf(xv1.y * mv1.y);
                pk.s[6] = f2bf(xv1.z * mv1.z); pk.s[7] = f2bf(xv1.w * mv1.w);
                *(bf16x8*)(dst + o * 16) = pk.v;
            }
        }
        __syncthreads();

        // ---- Ey phasors: i = i0 + g*4 + reg ----
        float eyR[4], eyI[4];
        {
            float sr, cr; __sincosf(t0, &sr, &cr);
            float sb, cb; __sincosf(t0 * (float)(i0 + g * 4 - 32), &sb, &cb);
            eyR[0] = cb; eyI[0] = -sb;
#pragma unroll
            for (int q = 1; q < 4; ++q) {
                const float nr = eyR[q-1] * cr + eyI[q-1] * sr;
                const float ni = eyI[q-1] * cr - eyR[q-1] * sr;
                eyR[q] = nr; eyI[q] = ni;
            }
        }

        // ---- this wave's 3 channels: MFMA + f32 Ey fold ----
#pragma unroll
        for (int cc = 0; cc < 3; ++cc) {
            const int ch = w * 3 + cc;
            const char* base = slds + ch * CHB + col * ROWB;
            const bf16x8 a0 = *(const bf16x8*)(base + g * 16);
            const bf16x8 a1 = *(const bf16x8*)(base + 64 + g * 16);
            f32x4 gre = {0.f, 0.f, 0.f, 0.f}, gim = {0.f, 0.f, 0.f, 0.f};
            gre = __builtin_amdgcn_mfma_f32_16x16x32_bf16(a0, breh[0], gre, 0, 0, 0);
            gre = __builtin_amdgcn_mfma_f32_16x16x32_bf16(a1, breh[1], gre, 0, 0, 0);
            gim = __builtin_amdgcn_mfma_f32_16x16x32_bf16(a0, bimh[0], gim, 0, 0, 0);
            gim = __builtin_amdgcn_mfma_f32_16x16x32_bf16(a1, bimh[1], gim, 0, 0, 0);
#pragma unroll
            for (int reg = 0; reg < 4; ++reg) {
                yre[cc] = fmaf(eyR[reg], gre[reg], fmaf(-eyI[reg], gim[reg], yre[cc]));
                yim[cc] = fmaf(eyR[reg], gim[reg], fmaf( eyI[reg], gre[reg], yim[cc]));
            }
        }
    }

    // ---- reduce over g-groups, park y in LDS ----
#pragma unroll
    for (int cc = 0; cc < 3; ++cc) {
        float vr = yre[cc], vi = yim[cc];
        vr += __shfl_xor(vr, 16); vi += __shfl_xor(vi, 16);
        vr += __shfl_xor(vr, 32); vi += __shfl_xor(vi, 32);
        if (g == 0) ylds[w * 3 + cc][col] = make_float2(vr, vi);
    }
    __syncthreads();

    // ---- fused combine epilogue (planar f32 out, proven layout) ----
    bool is64 = true;
#pragma unroll
    for (int i = 1; i < 32; i += 2) is64 = is64 && (sidx[i] == 0);

#pragma unroll
    for (int q = 0; q < 8; ++q) {
        const int item = tid + q * 256;         // 32t x 4c x 16k = 2048
        const int kl = item & 15;
        const int c  = (item >> 4) & 3;
        const int t  = item >> 6;
        const int rt = is64 ? sidx[2 * t] : sidx[t];
        if (rt == r) {
            const float d = dcf[r * NK + k0 + kl];
            float ore = 0.f, oim = 0.f;
#pragma unroll
            for (int a = 0; a < NA; ++a) {
                const float p = phi[a * NT + t];
                const float2 v = ylds[a * 4 + c][kl];
                ore = fmaf(p, v.x, ore);
                oim = fmaf(p, v.y, oim);
            }
            const int gid = t * 4096 + c * 1024 + k0 + kl;
            out[gid]        = ore * d;
            out[NOUT + gid] = oim * d;
        }
    }
}

// ---------------------------------------------------------------------------
extern "C" void kernel_launch(void* const* d_in, const int* in_sizes, int n_in,
                              void* d_out, int out_size, void* d_ws, size_t ws_size,
                              hipStream_t stream) {
    // size-signature input resolution (robust to permutation; doc order default)
    int ix = 0, i16a = 1, iphi = 2, i16b = 3, idcf = 4, isidx = 5;
    int f16[2]; int n16 = 0, fx = -1, fphi = -1, fdcf = -1, fsidx = -1;
    for (int i = 0; i < n_in; ++i) {
        const int s = in_sizes[i];
        if (s == 12288) fx = i;
        else if (s == 96) fphi = i;
        else if (s == 8192) fdcf = i;
        else if (s == 16384) { if (n16 < 2) f16[n16] = i; ++n16; }
        else if (s == 32 || s == 64) fsidx = i;
    }
    if (fx >= 0 && fphi >= 0 && fdcf >= 0 && fsidx >= 0 && n16 == 2) {
        ix = fx; iphi = fphi; idcf = fdcf; isidx = fsidx;
        i16a = f16[0]; i16b = f16[1];
    }

    const float* x    = (const float*)d_in[ix];
    const float* cA   = (const float*)d_in[i16a];
    const float* cB   = (const float*)d_in[i16b];
    const float* phi  = (const float*)d_in[iphi];
    const float* dcf  = (const float*)d_in[idcf];
    const int*   sidx = (const int*)d_in[isidx];

    int* flag16 = (int*)d_ws;

    detect16<<<16, 256, 0, stream>>>(cA, flag16);
    nudft_fused<<<NRK / 16, 256, 0, stream>>>(x, cA, cB, flag16, phi, dcf, sidx,
                                              (float*)d_out);
}

// Round 14
// 27.917 us; speedup vs baseline: 1.2347x; 1.2347x over previous
//
#include <hip/hip_runtime.h>
#include <hip/hip_bf16.h>

#define NA 3
#define NT 32
#define NC 4
#define NR 8
#define NK 1024
#define NPIX 4096            // 64*64
#define NOUT (NT * NC * NK)  // 131072 complex outputs
#define NRK (NR * NK)        // 8192 (r,k) pairs

// workspace byte offsets
#define SP_OFF 0                          // s'pack [12][4096] bf16   = 98304 B
#define EX_OFF 98304                      // Ex [8192][re64|im64] bf16 = 2 MiB
#define EY_OFF (98304 + 2097152)          // Ey [8192][64] complex f32 = 4 MiB

typedef __attribute__((ext_vector_type(8))) short bf16x8;
typedef __attribute__((ext_vector_type(4))) float f32x4;

static __device__ __forceinline__ short f2bf(float f) {
    union { __hip_bfloat16 h; short s; } u;
    u.h = __float2bfloat16(f);
    return u.s;
}

// ---------------------------------------------------------------------------
// prep_all: detect prologue (per-block scan of candA; |v|>pi => candA is mps,
// proven r7-r13) + 22528 one-shot jobs:
//   [0, 8192):      Ex[rk][j] = exp(-i*t1*(j-32))  -> bf16 re[64]|im[64]
//   [8192, 16384):  Ey[rk][i] = exp(-i*t0*(i-32))  -> complex f32 [64]
//   [16384, 22528): s'pack: ch=job/512, 8 px: bf16(x[a]*mps[c])
// Phasors use sincos anchors at {0,16,32,48} (chains <= 15 steps).
// ---------------------------------------------------------------------------
__global__ __launch_bounds__(256) void prep_all(
    const float* __restrict__ x,
    const float* __restrict__ candA,
    const float* __restrict__ candB,
    short* __restrict__ sp,
    short* __restrict__ ex,
    float* __restrict__ ey)
{
    __shared__ int sfl;
    if (threadIdx.x == 0) sfl = 0;
    __syncthreads();
    {
        const float4* A4 = (const float4*)candA;
        int loc = 0;
        for (int i = threadIdx.x; i < 4096; i += 256) {
            const float4 v = A4[i];
            if (fabsf(v.x) > 3.1416f || fabsf(v.y) > 3.1416f ||
                fabsf(v.z) > 3.1416f || fabsf(v.w) > 3.1416f) loc = 1;
        }
        if (loc) atomicOr(&sfl, 1);
    }
    __syncthreads();
    const int fl = sfl;
    const float* __restrict__ trj = fl ? candB : candA;
    const float* __restrict__ mps = fl ? candA : candB;

    const int job = blockIdx.x * 256 + threadIdx.x;
    if (job < NRK) {
        // ---- Ex ----
        const int r = job >> 10, k = job & (NK - 1);
        const float t1 = trj[(r * 2 + 1) * NK + k];
        float s1, c1;   __sincosf(t1, &s1, &c1);
        float s16, c16; __sincosf(16.f * t1, &s16, &c16);
        float s32, c32; __sincosf(32.f * t1, &s32, &c32);
        // anchors exp(-i*t1*(16*seg-32)): seg0=(c32,s32) seg1=(c16,s16)
        // seg2=(1,0) seg3=(c16,-s16); step rot = exp(-i*t1)
        const float aR[4] = {c32, c16, 1.f, c16}, aI[4] = {s32, s16, 0.f, -s16};
        short* dst = ex + job * 128;
#pragma unroll
        for (int seg = 0; seg < 4; ++seg) {
            float pr = aR[seg], pi = aI[seg];
            union { bf16x8 v; short s[8]; } bre, bim;
#pragma unroll
            for (int e = 0; e < 16; ++e) {
                bre.s[e & 7] = f2bf(pr); bim.s[e & 7] = f2bf(pi);
                const float nr = fmaf(pr, c1, pi * s1);
                const float ni = fmaf(pi, c1, -pr * s1);
                pr = nr; pi = ni;
                if ((e & 7) == 7) {
                    *(bf16x8*)(dst + seg * 16 + (e >> 3) * 8) = bre.v;
                    *(bf16x8*)(dst + 64 + seg * 16 + (e >> 3) * 8) = bim.v;
                }
            }
        }
    } else if (job < 2 * NRK) {
        // ---- Ey ----
        const int rk = job - NRK, r = rk >> 10, k = rk & (NK - 1);
        const float t0 = trj[(r * 2 + 0) * NK + k];
        float s1, c1;   __sincosf(t0, &s1, &c1);
        float s16, c16; __sincosf(16.f * t0, &s16, &c16);
        float s32, c32; __sincosf(32.f * t0, &s32, &c32);
        const float aR[4] = {c32, c16, 1.f, c16}, aI[4] = {s32, s16, 0.f, -s16};
        float* dst = ey + rk * 128;
#pragma unroll
        for (int seg = 0; seg < 4; ++seg) {
            float pr = aR[seg], pi = aI[seg];
            float4 buf;
#pragma unroll
            for (int e = 0; e < 16; ++e) {
                if (e & 1) {
                    buf.z = pr; buf.w = pi;
                    *(float4*)(dst + seg * 32 + (e - 1) * 2) = buf;
                } else { buf.x = pr; buf.y = pi; }
                const float nr = fmaf(pr, c1, pi * s1);
                const float ni = fmaf(pi, c1, -pr * s1);
                pr = nr; pi = ni;
            }
        }
    } else {
        // ---- s'pack ----
        const int j2 = job - 2 * NRK;           // [0, 6144)
        const int ch = j2 >> 9, p8 = (j2 & 511) * 8;
        const int a = ch >> 2, c = ch & 3;
        const float4 xv0 = *(const float4*)&x[a * NPIX + p8];
        const float4 xv1 = *(const float4*)&x[a * NPIX + p8 + 4];
        const float4 mv0 = *(const float4*)&mps[c * NPIX + p8];
        const float4 mv1 = *(const float4*)&mps[c * NPIX + p8 + 4];
        union { bf16x8 v; short s[8]; } pk;
        pk.s[0] = f2bf(xv0.x * mv0.x); pk.s[1] = f2bf(xv0.y * mv0.y);
        pk.s[2] = f2bf(xv0.z * mv0.z); pk.s[3] = f2bf(xv0.w * mv0.w);
        pk.s[4] = f2bf(xv1.x * mv1.x); pk.s[5] = f2bf(xv1.y * mv1.y);
        pk.s[6] = f2bf(xv1.z * mv1.z); pk.s[7] = f2bf(xv1.w * mv1.w);
        *(bf16x8*)(sp + ch * NPIX + p8) = pk.v;
    }
}

// ---------------------------------------------------------------------------
// nudft_final: barrier-free separable NUDFT + fused combine.
// Block = 16 rk (r = bx>>6, k0 = (bx&63)*16); 4 waves x 3 channels.
//   G[i16, rk16] = sum_j s'[ch,i,j]*Ex[j,rk]  (2 MFMAs, K=64, from global)
//   y[ch,rk] += Ey[i,rk]*G   (f32)    over 4 i-slices
// Lane rule (A/B identical j-slots = g*8+e+32h -> HW-permutation invariant,
// r11/r12-proven); C row = g*4+reg (m89). Epilogue = r13's proven fused
// combine: planar f32 out (r7-proven layout).
// ---------------------------------------------------------------------------
__global__ __launch_bounds__(256) void nudft_final(
    const short* __restrict__ sp,
    const short* __restrict__ ex,
    const float* __restrict__ ey,
    const float* __restrict__ phi,
    const float* __restrict__ dcf,
    const int*  __restrict__ sidx,
    float* __restrict__ out)
{
    __shared__ float2 ylds[12][16];
    const int tid = threadIdx.x;
    const int w = tid >> 6, l = tid & 63, col = l & 15, g = l >> 4;
    const int rk0 = blockIdx.x * 16;
    const int r = rk0 >> 10, k0 = rk0 & (NK - 1);
    const int rk = rk0 + col;

    const short* exp_ = ex + rk * 128;
    const bf16x8 bre0 = *(const bf16x8*)(exp_ + g * 8);
    const bf16x8 bre1 = *(const bf16x8*)(exp_ + 32 + g * 8);
    const bf16x8 bim0 = *(const bf16x8*)(exp_ + 64 + g * 8);
    const bf16x8 bim1 = *(const bf16x8*)(exp_ + 96 + g * 8);

    float yre[3] = {0.f, 0.f, 0.f}, yim[3] = {0.f, 0.f, 0.f};
#pragma unroll
    for (int sl = 0; sl < 4; ++sl) {
        const float* ep = ey + rk * 128 + sl * 32 + g * 8;
        const float4 e01 = *(const float4*)ep;
        const float4 e23 = *(const float4*)(ep + 4);
        const float eyR[4] = {e01.x, e01.z, e23.x, e23.z};
        const float eyI[4] = {e01.y, e01.w, e23.y, e23.w};
#pragma unroll
        for (int cc = 0; cc < 3; ++cc) {
            const int ch = w * 3 + cc;
            const short* ap = sp + ch * NPIX + (sl * 16 + col) * 64 + g * 8;
            const bf16x8 a0 = *(const bf16x8*)ap;
            const bf16x8 a1 = *(const bf16x8*)(ap + 32);
            f32x4 gre = {0.f, 0.f, 0.f, 0.f}, gim = {0.f, 0.f, 0.f, 0.f};
            gre = __builtin_amdgcn_mfma_f32_16x16x32_bf16(a0, bre0, gre, 0, 0, 0);
            gre = __builtin_amdgcn_mfma_f32_16x16x32_bf16(a1, bre1, gre, 0, 0, 0);
            gim = __builtin_amdgcn_mfma_f32_16x16x32_bf16(a0, bim0, gim, 0, 0, 0);
            gim = __builtin_amdgcn_mfma_f32_16x16x32_bf16(a1, bim1, gim, 0, 0, 0);
#pragma unroll
            for (int reg = 0; reg < 4; ++reg) {
                yre[cc] = fmaf(eyR[reg], gre[reg], fmaf(-eyI[reg], gim[reg], yre[cc]));
                yim[cc] = fmaf(eyR[reg], gim[reg], fmaf( eyI[reg], gre[reg], yim[cc]));
            }
        }
    }

    // reduce over g (lane bits 4,5), park in LDS
#pragma unroll
    for (int cc = 0; cc < 3; ++cc) {
        float vr = yre[cc], vi = yim[cc];
        vr += __shfl_xor(vr, 16); vi += __shfl_xor(vi, 16);
        vr += __shfl_xor(vr, 32); vi += __shfl_xor(vi, 32);
        if (g == 0) ylds[w * 3 + cc][col] = make_float2(vr, vi);
    }
    __syncthreads();

    // fused combine epilogue (r13-proven)
    bool is64 = true;
#pragma unroll
    for (int i = 1; i < 32; i += 2) is64 = is64 && (sidx[i] == 0);
#pragma unroll
    for (int q = 0; q < 8; ++q) {
        const int item = tid + q * 256;          // 32t x 4c x 16k
        const int kl = item & 15;
        const int c  = (item >> 4) & 3;
        const int t  = item >> 6;
        const int rt = is64 ? sidx[2 * t] : sidx[t];
        if (rt == r) {
            const float d = dcf[r * NK + k0 + kl];
            float ore = 0.f, oim = 0.f;
#pragma unroll
            for (int a = 0; a < NA; ++a) {
                const float p = phi[a * NT + t];
                const float2 v = ylds[a * 4 + c][kl];
                ore = fmaf(p, v.x, ore);
                oim = fmaf(p, v.y, oim);
            }
            const int gid = t * 4096 + c * 1024 + k0 + kl;
            out[gid]        = ore * d;
            out[NOUT + gid] = oim * d;
        }
    }
}

// ---------------------------------------------------------------------------
extern "C" void kernel_launch(void* const* d_in, const int* in_sizes, int n_in,
                              void* d_out, int out_size, void* d_ws, size_t ws_size,
                              hipStream_t stream) {
    // size-signature input resolution (robust to permutation; doc order default)
    int ix = 0, i16a = 1, iphi = 2, i16b = 3, idcf = 4, isidx = 5;
    int f16[2]; int n16 = 0, fx = -1, fphi = -1, fdcf = -1, fsidx = -1;
    for (int i = 0; i < n_in; ++i) {
        const int s = in_sizes[i];
        if (s == 12288) fx = i;
        else if (s == 96) fphi = i;
        else if (s == 8192) fdcf = i;
        else if (s == 16384) { if (n16 < 2) f16[n16] = i; ++n16; }
        else if (s == 32 || s == 64) fsidx = i;
    }
    if (fx >= 0 && fphi >= 0 && fdcf >= 0 && fsidx >= 0 && n16 == 2) {
        ix = fx; iphi = fphi; idcf = fdcf; isidx = fsidx;
        i16a = f16[0]; i16b = f16[1];
    }

    const float* x    = (const float*)d_in[ix];
    const float* cA   = (const float*)d_in[i16a];
    const float* cB   = (const float*)d_in[i16b];
    const float* phi  = (const float*)d_in[iphi];
    const float* dcf  = (const float*)d_in[idcf];
    const int*   sidx = (const int*)d_in[isidx];

    short* sp = (short*)((char*)d_ws + SP_OFF);
    short* ex = (short*)((char*)d_ws + EX_OFF);
    float* ey = (float*)((char*)d_ws + EY_OFF);

    prep_all<<<(2 * NRK + 6144) / 256, 256, 0, stream>>>(x, cA, cB, sp, ex, ey);
    nudft_final<<<NRK / 16, 256, 0, stream>>>(sp, ex, ey, phi, dcf, sidx,
                                              (float*)d_out);
}

// Round 15
// 19.461 us; speedup vs baseline: 1.7711x; 1.4345x over previous
//
#include <hip/hip_runtime.h>
#include <hip/hip_bf16.h>

#define NA 3
#define NT 32
#define NC 4
#define NR 8
#define NK 1024
#define NPIX 4096            // 64*64
#define NOUT (NT * NC * NK)  // 131072 complex outputs
#define NRK (NR * NK)        // 8192 (r,k) pairs

typedef __attribute__((ext_vector_type(8))) short bf16x8;
typedef __attribute__((ext_vector_type(4))) float f32x4;

static __device__ __forceinline__ short f2bf(float f) {
    union { __hip_bfloat16 h; short s; } u;
    u.h = __float2bfloat16(f);
    return u.s;
}

// ---------------------------------------------------------------------------
// prep_pack: 24 blocks. Each block independently scans ALL of candA for
// |v| > pi (candA==mps ~N(0,1): hit w.p. 1-2e-12; candA==trj: never) --
// detect semantics proven r7-r14. Block 0 publishes the flag. Then the
// block's 256 threads each pack 8 pixels: sp[ch][n] = bf16(x[a,n]*mps[c,n]).
// ---------------------------------------------------------------------------
__global__ __launch_bounds__(256) void prep_pack(
    const float* __restrict__ x,
    const float* __restrict__ candA,
    const float* __restrict__ candB,
    int* __restrict__ flag,
    short* __restrict__ sp)
{
    __shared__ int sfl;
    if (threadIdx.x == 0) sfl = 0;
    __syncthreads();
    {
        const float4* A4 = (const float4*)candA;
        int loc = 0;
        for (int i = threadIdx.x; i < 4096; i += 256) {
            const float4 v = A4[i];
            if (fabsf(v.x) > 3.1416f || fabsf(v.y) > 3.1416f ||
                fabsf(v.z) > 3.1416f || fabsf(v.w) > 3.1416f) loc = 1;
        }
        if (loc) atomicOr(&sfl, 1);
    }
    __syncthreads();
    const int fl = sfl;
    if (blockIdx.x == 0 && threadIdx.x == 0) flag[0] = fl;
    const float* __restrict__ mps = fl ? candA : candB;

    const int job = blockIdx.x * 256 + threadIdx.x;   // 0..6143
    const int ch = job >> 9, p8 = (job & 511) * 8;
    const int a = ch >> 2, c = ch & 3;
    const float4 xv0 = *(const float4*)&x[a * NPIX + p8];
    const float4 xv1 = *(const float4*)&x[a * NPIX + p8 + 4];
    const float4 mv0 = *(const float4*)&mps[c * NPIX + p8];
    const float4 mv1 = *(const float4*)&mps[c * NPIX + p8 + 4];
    union { bf16x8 v; short s[8]; } pk;
    pk.s[0] = f2bf(xv0.x * mv0.x); pk.s[1] = f2bf(xv0.y * mv0.y);
    pk.s[2] = f2bf(xv0.z * mv0.z); pk.s[3] = f2bf(xv0.w * mv0.w);
    pk.s[4] = f2bf(xv1.x * mv1.x); pk.s[5] = f2bf(xv1.y * mv1.y);
    pk.s[6] = f2bf(xv1.z * mv1.z); pk.s[7] = f2bf(xv1.w * mv1.w);
    *(bf16x8*)(sp + ch * NPIX + p8) = pk.v;
}

// ---------------------------------------------------------------------------
// nudft_all: separable NUDFT, in-register phasors, fused combine.
// Block = 16 rk (r = bx>>6, k0 = (bx&63)*16); 4 waves x 3 channels each.
//   Ex[j] = exp(-i*t1*(j-32)) generated in-register (r12-proven chains);
//   G[i16, rk16] = sum_j s'[ch,i,j]*Ex[j,rk]  (2 MFMAs, K=64, A from global sp)
//   y[ch,rk] += Ey[i,rk]*G  in f32, Ey in-register (r12-proven).
// Lane rule (A/B identical j-slots = g*8+e+32h -> HW-permutation invariant,
// r11/r12); C row = g*4+reg (m89-verified). Epilogue: fused combine, planar
// f32 out (r13/r14-proven).  No barriers until the epilogue.
// ---------------------------------------------------------------------------
__global__ __launch_bounds__(256) void nudft_all(
    const short* __restrict__ sp,
    const float* __restrict__ candA,
    const float* __restrict__ candB,
    const int*  __restrict__ flag,
    const float* __restrict__ phi,
    const float* __restrict__ dcf,
    const int*  __restrict__ sidx,
    float* __restrict__ out)
{
    __shared__ float2 ylds[12][16];

    const float* __restrict__ trj = flag[0] ? candB : candA;

    const int tid = threadIdx.x;
    const int w = tid >> 6, l = tid & 63, col = l & 15, g = l >> 4;
    const int rk0 = blockIdx.x * 16;
    const int r = rk0 >> 10, k0 = rk0 & (NK - 1);
    const int k = k0 + col;

    const float t0 = trj[(r * 2 + 0) * NK + k];
    const float t1 = trj[(r * 2 + 1) * NK + k];

    // ---- Ex fragments in-register (r12-proven) ----
    bf16x8 breh[2], bimh[2];
    {
        float pr[8], pi[8];
        float sr, cr; __sincosf(t1, &sr, &cr);
        float s0, c0; __sincosf(t1 * (float)(g * 8 - 32), &s0, &c0);
        pr[0] = c0; pi[0] = -s0;
#pragma unroll
        for (int e = 1; e < 8; ++e) {
            const float nr = pr[e-1] * cr + pi[e-1] * sr;
            const float ni = pi[e-1] * cr - pr[e-1] * sr;
            pr[e] = nr; pi[e] = ni;
        }
        union { bf16x8 v; short s[8]; } u0, u1;
#pragma unroll
        for (int e = 0; e < 8; ++e) { u0.s[e] = f2bf(pr[e]); u1.s[e] = f2bf(pi[e]); }
        breh[0] = u0.v; bimh[0] = u1.v;
        float s32, c32; __sincosf(32.f * t1, &s32, &c32);
#pragma unroll
        for (int e = 0; e < 8; ++e) {
            const float nr = pr[e] * c32 + pi[e] * s32;
            const float ni = pi[e] * c32 - pr[e] * s32;
            u0.s[e] = f2bf(nr); u1.s[e] = f2bf(ni);
        }
        breh[1] = u0.v; bimh[1] = u1.v;
    }

    // ---- Ey step rotation hoisted ----
    float syr, cyr; __sincosf(t0, &syr, &cyr);

    float yre[3] = {0.f, 0.f, 0.f}, yim[3] = {0.f, 0.f, 0.f};
#pragma unroll
    for (int sl = 0; sl < 4; ++sl) {
        const int i0 = sl * 16;
        // Ey phasors: i = i0 + g*4 + reg (r12-proven)
        float eyR[4], eyI[4];
        {
            float sb, cb; __sincosf(t0 * (float)(i0 + g * 4 - 32), &sb, &cb);
            eyR[0] = cb; eyI[0] = -sb;
#pragma unroll
            for (int q = 1; q < 4; ++q) {
                const float nr = eyR[q-1] * cyr + eyI[q-1] * syr;
                const float ni = eyI[q-1] * cyr - eyR[q-1] * syr;
                eyR[q] = nr; eyI[q] = ni;
            }
        }
#pragma unroll
        for (int cc = 0; cc < 3; ++cc) {
            const int ch = w * 3 + cc;
            const short* ap = sp + ch * NPIX + (i0 + col) * 64 + g * 8;
            const bf16x8 a0 = *(const bf16x8*)ap;
            const bf16x8 a1 = *(const bf16x8*)(ap + 32);
            f32x4 gre = {0.f, 0.f, 0.f, 0.f}, gim = {0.f, 0.f, 0.f, 0.f};
            gre = __builtin_amdgcn_mfma_f32_16x16x32_bf16(a0, breh[0], gre, 0, 0, 0);
            gre = __builtin_amdgcn_mfma_f32_16x16x32_bf16(a1, breh[1], gre, 0, 0, 0);
            gim = __builtin_amdgcn_mfma_f32_16x16x32_bf16(a0, bimh[0], gim, 0, 0, 0);
            gim = __builtin_amdgcn_mfma_f32_16x16x32_bf16(a1, bimh[1], gim, 0, 0, 0);
#pragma unroll
            for (int reg = 0; reg < 4; ++reg) {
                yre[cc] = fmaf(eyR[reg], gre[reg], fmaf(-eyI[reg], gim[reg], yre[cc]));
                yim[cc] = fmaf(eyR[reg], gim[reg], fmaf( eyI[reg], gre[reg], yim[cc]));
            }
        }
    }

    // ---- reduce over g (lane bits 4,5), park in LDS ----
#pragma unroll
    for (int cc = 0; cc < 3; ++cc) {
        float vr = yre[cc], vi = yim[cc];
        vr += __shfl_xor(vr, 16); vi += __shfl_xor(vi, 16);
        vr += __shfl_xor(vr, 32); vi += __shfl_xor(vi, 32);
        if (g == 0) ylds[w * 3 + cc][col] = make_float2(vr, vi);
    }
    __syncthreads();

    // ---- fused combine epilogue (r13/r14-proven; planar f32 out r7-proven) ----
    bool is64 = true;
#pragma unroll
    for (int i = 1; i < 32; i += 2) is64 = is64 && (sidx[i] == 0);
#pragma unroll
    for (int q = 0; q < 8; ++q) {
        const int item = tid + q * 256;          // 32t x 4c x 16k
        const int kl = item & 15;
        const int c  = (item >> 4) & 3;
        const int t  = item >> 6;
        const int rt = is64 ? sidx[2 * t] : sidx[t];
        if (rt == r) {
            const float d = dcf[r * NK + k0 + kl];
            float ore = 0.f, oim = 0.f;
#pragma unroll
            for (int a = 0; a < NA; ++a) {
                const float p = phi[a * NT + t];
                const float2 v = ylds[a * 4 + c][kl];
                ore = fmaf(p, v.x, ore);
                oim = fmaf(p, v.y, oim);
            }
            const int gid = t * 4096 + c * 1024 + k0 + kl;
            out[gid]        = ore * d;
            out[NOUT + gid] = oim * d;
        }
    }
}

// ---------------------------------------------------------------------------
extern "C" void kernel_launch(void* const* d_in, const int* in_sizes, int n_in,
                              void* d_out, int out_size, void* d_ws, size_t ws_size,
                              hipStream_t stream) {
    // size-signature input resolution (robust to permutation; doc order default)
    int ix = 0, i16a = 1, iphi = 2, i16b = 3, idcf = 4, isidx = 5;
    int f16[2]; int n16 = 0, fx = -1, fphi = -1, fdcf = -1, fsidx = -1;
    for (int i = 0; i < n_in; ++i) {
        const int s = in_sizes[i];
        if (s == 12288) fx = i;
        else if (s == 96) fphi = i;
        else if (s == 8192) fdcf = i;
        else if (s == 16384) { if (n16 < 2) f16[n16] = i; ++n16; }
        else if (s == 32 || s == 64) fsidx = i;
    }
    if (fx >= 0 && fphi >= 0 && fdcf >= 0 && fsidx >= 0 && n16 == 2) {
        ix = fx; iphi = fphi; idcf = fdcf; isidx = fsidx;
        i16a = f16[0]; i16b = f16[1];
    }

    const float* x    = (const float*)d_in[ix];
    const float* cA   = (const float*)d_in[i16a];
    const float* cB   = (const float*)d_in[i16b];
    const float* phi  = (const float*)d_in[iphi];
    const float* dcf  = (const float*)d_in[idcf];
    const int*   sidx = (const int*)d_in[isidx];

    int*   flag = (int*)d_ws;                     // 256-B slot
    short* sp   = (short*)((char*)d_ws + 256);    // [12][4096] bf16 = 98304 B

    prep_pack<<<24, 256, 0, stream>>>(x, cA, cB, flag, sp);
    nudft_all<<<NRK / 16, 256, 0, stream>>>(sp, cA, cB, flag, phi, dcf, sidx,
                                            (float*)d_out);
}

// Round 16
// 18.626 us; speedup vs baseline: 1.8506x; 1.0448x over previous
//
#include <hip/hip_runtime.h>
#include <hip/hip_bf16.h>

#define NA 3
#define NT 32
#define NC 4
#define NR 8
#define NK 1024
#define NPIX 4096            // 64*64
#define NOUT (NT * NC * NK)  // 131072 complex outputs
#define NRK (NR * NK)        // 8192 (r,k) pairs

typedef __attribute__((ext_vector_type(8))) short bf16x8;
typedef __attribute__((ext_vector_type(4))) float f32x4;

static __device__ __forceinline__ short f2bf(float f) {
    union { __hip_bfloat16 h; short s; } u;
    u.h = __float2bfloat16(f);
    return u.s;
}

// ---------------------------------------------------------------------------
// prep_pack: 24 blocks. Per-block detect scan of candA (|v|>pi => candA is
// mps; proven r7-r15), block 0 publishes flag; then 6144 pack jobs:
// sp[ch][n] = bf16(x[a,n]*mps[c,n]).   [byte-identical to r15]
// ---------------------------------------------------------------------------
__global__ __launch_bounds__(256) void prep_pack(
    const float* __restrict__ x,
    const float* __restrict__ candA,
    const float* __restrict__ candB,
    int* __restrict__ flag,
    short* __restrict__ sp)
{
    __shared__ int sfl;
    if (threadIdx.x == 0) sfl = 0;
    __syncthreads();
    {
        const float4* A4 = (const float4*)candA;
        int loc = 0;
        for (int i = threadIdx.x; i < 4096; i += 256) {
            const float4 v = A4[i];
            if (fabsf(v.x) > 3.1416f || fabsf(v.y) > 3.1416f ||
                fabsf(v.z) > 3.1416f || fabsf(v.w) > 3.1416f) loc = 1;
        }
        if (loc) atomicOr(&sfl, 1);
    }
    __syncthreads();
    const int fl = sfl;
    if (blockIdx.x == 0 && threadIdx.x == 0) flag[0] = fl;
    const float* __restrict__ mps = fl ? candA : candB;

    const int job = blockIdx.x * 256 + threadIdx.x;   // 0..6143
    const int ch = job >> 9, p8 = (job & 511) * 8;
    const int a = ch >> 2, c = ch & 3;
    const float4 xv0 = *(const float4*)&x[a * NPIX + p8];
    const float4 xv1 = *(const float4*)&x[a * NPIX + p8 + 4];
    const float4 mv0 = *(const float4*)&mps[c * NPIX + p8];
    const float4 mv1 = *(const float4*)&mps[c * NPIX + p8 + 4];
    union { bf16x8 v; short s[8]; } pk;
    pk.s[0] = f2bf(xv0.x * mv0.x); pk.s[1] = f2bf(xv0.y * mv0.y);
    pk.s[2] = f2bf(xv0.z * mv0.z); pk.s[3] = f2bf(xv0.w * mv0.w);
    pk.s[4] = f2bf(xv1.x * mv1.x); pk.s[5] = f2bf(xv1.y * mv1.y);
    pk.s[6] = f2bf(xv1.z * mv1.z); pk.s[7] = f2bf(xv1.w * mv1.w);
    *(bf16x8*)(sp + ch * NPIX + p8) = pk.v;
}

// ---------------------------------------------------------------------------
// nudft_all8: r15's separable NUDFT with 8-wave work split for occupancy.
// Block = 16 rk, 512 thr = 8 waves; wave w -> (chgrp = w&3 -> 3 channels,
// ihalf = w>>2 -> 2 i-slices of 16).  Per wave: in-register Ex fragments
// (r12/r15-proven chains), Ey phasors per slice, A-fragments from global sp,
// 2 MFMAs (K=64) per (ch, slice), f32 Ey-fold.  Partial y per ihalf ->
// ylds[2][12][16]; fused combine epilogue sums the halves (planar f32 out,
// proven r7-r15).  Lane rule: A/B j-slots = g*8+e+32h (HW-perm invariant,
// r11-proven); C row = g*4+reg (m89-verified).
// ---------------------------------------------------------------------------
__global__ __launch_bounds__(512, 4) void nudft_all8(
    const short* __restrict__ sp,
    const float* __restrict__ candA,
    const float* __restrict__ candB,
    const int*  __restrict__ flag,
    const float* __restrict__ phi,
    const float* __restrict__ dcf,
    const int*  __restrict__ sidx,
    float* __restrict__ out)
{
    __shared__ float2 ylds[2][12][16];

    const float* __restrict__ trj = flag[0] ? candB : candA;

    const int tid = threadIdx.x;
    const int w = tid >> 6, l = tid & 63, col = l & 15, g = l >> 4;
    const int chgrp = w & 3, ihalf = w >> 2;
    const int rk0 = blockIdx.x * 16;
    const int r = rk0 >> 10, k0 = rk0 & (NK - 1);
    const int k = k0 + col;

    const float t0 = trj[(r * 2 + 0) * NK + k];
    const float t1 = trj[(r * 2 + 1) * NK + k];

    // ---- Ex fragments in-register (r12/r15-proven) ----
    bf16x8 breh[2], bimh[2];
    {
        float pr[8], pi[8];
        float sr, cr; __sincosf(t1, &sr, &cr);
        float s0, c0; __sincosf(t1 * (float)(g * 8 - 32), &s0, &c0);
        pr[0] = c0; pi[0] = -s0;
#pragma unroll
        for (int e = 1; e < 8; ++e) {
            const float nr = pr[e-1] * cr + pi[e-1] * sr;
            const float ni = pi[e-1] * cr - pr[e-1] * sr;
            pr[e] = nr; pi[e] = ni;
        }
        union { bf16x8 v; short s[8]; } u0, u1;
#pragma unroll
        for (int e = 0; e < 8; ++e) { u0.s[e] = f2bf(pr[e]); u1.s[e] = f2bf(pi[e]); }
        breh[0] = u0.v; bimh[0] = u1.v;
        float s32, c32; __sincosf(32.f * t1, &s32, &c32);
#pragma unroll
        for (int e = 0; e < 8; ++e) {
            const float nr = pr[e] * c32 + pi[e] * s32;
            const float ni = pi[e] * c32 - pr[e] * s32;
            u0.s[e] = f2bf(nr); u1.s[e] = f2bf(ni);
        }
        breh[1] = u0.v; bimh[1] = u1.v;
    }

    // ---- Ey step rotation hoisted ----
    float syr, cyr; __sincosf(t0, &syr, &cyr);

    float yre[3] = {0.f, 0.f, 0.f}, yim[3] = {0.f, 0.f, 0.f};
#pragma unroll
    for (int sl = 0; sl < 2; ++sl) {
        const int i0 = ihalf * 32 + sl * 16;
        // Ey phasors: i = i0 + g*4 + reg (r12/r15-proven)
        float eyR[4], eyI[4];
        {
            float sb, cb; __sincosf(t0 * (float)(i0 + g * 4 - 32), &sb, &cb);
            eyR[0] = cb; eyI[0] = -sb;
#pragma unroll
            for (int q = 1; q < 4; ++q) {
                const float nr = eyR[q-1] * cyr + eyI[q-1] * syr;
                const float ni = eyI[q-1] * cyr - eyR[q-1] * syr;
                eyR[q] = nr; eyI[q] = ni;
            }
        }
#pragma unroll
        for (int cc = 0; cc < 3; ++cc) {
            const int ch = chgrp * 3 + cc;
            const short* ap = sp + ch * NPIX + (i0 + col) * 64 + g * 8;
            const bf16x8 a0 = *(const bf16x8*)ap;
            const bf16x8 a1 = *(const bf16x8*)(ap + 32);
            f32x4 gre = {0.f, 0.f, 0.f, 0.f}, gim = {0.f, 0.f, 0.f, 0.f};
            gre = __builtin_amdgcn_mfma_f32_16x16x32_bf16(a0, breh[0], gre, 0, 0, 0);
            gre = __builtin_amdgcn_mfma_f32_16x16x32_bf16(a1, breh[1], gre, 0, 0, 0);
            gim = __builtin_amdgcn_mfma_f32_16x16x32_bf16(a0, bimh[0], gim, 0, 0, 0);
            gim = __builtin_amdgcn_mfma_f32_16x16x32_bf16(a1, bimh[1], gim, 0, 0, 0);
#pragma unroll
            for (int reg = 0; reg < 4; ++reg) {
                yre[cc] = fmaf(eyR[reg], gre[reg], fmaf(-eyI[reg], gim[reg], yre[cc]));
                yim[cc] = fmaf(eyR[reg], gim[reg], fmaf( eyI[reg], gre[reg], yim[cc]));
            }
        }
    }

    // ---- reduce over g (lane bits 4,5), park partials in LDS ----
#pragma unroll
    for (int cc = 0; cc < 3; ++cc) {
        float vr = yre[cc], vi = yim[cc];
        vr += __shfl_xor(vr, 16); vi += __shfl_xor(vi, 16);
        vr += __shfl_xor(vr, 32); vi += __shfl_xor(vi, 32);
        if (g == 0) ylds[ihalf][chgrp * 3 + cc][col] = make_float2(vr, vi);
    }
    __syncthreads();

    // ---- fused combine epilogue (r13-r15-proven; sums the 2 i-halves) ----
    bool is64 = true;
#pragma unroll
    for (int i = 1; i < 32; i += 2) is64 = is64 && (sidx[i] == 0);
#pragma unroll
    for (int q = 0; q < 4; ++q) {
        const int item = tid + q * 512;          // 32t x 4c x 16k = 2048
        const int kl = item & 15;
        const int c  = (item >> 4) & 3;
        const int t  = item >> 6;
        const int rt = is64 ? sidx[2 * t] : sidx[t];
        if (rt == r) {
            const float d = dcf[r * NK + k0 + kl];
            float ore = 0.f, oim = 0.f;
#pragma unroll
            for (int a = 0; a < NA; ++a) {
                const float p = phi[a * NT + t];
                const float2 v0 = ylds[0][a * 4 + c][kl];
                const float2 v1 = ylds[1][a * 4 + c][kl];
                ore = fmaf(p, v0.x + v1.x, ore);
                oim = fmaf(p, v0.y + v1.y, oim);
            }
            const int gid = t * 4096 + c * 1024 + k0 + kl;
            out[gid]        = ore * d;
            out[NOUT + gid] = oim * d;
        }
    }
}

// ---------------------------------------------------------------------------
extern "C" void kernel_launch(void* const* d_in, const int* in_sizes, int n_in,
                              void* d_out, int out_size, void* d_ws, size_t ws_size,
                              hipStream_t stream) {
    // size-signature input resolution (robust to permutation; doc order default)
    int ix = 0, i16a = 1, iphi = 2, i16b = 3, idcf = 4, isidx = 5;
    int f16[2]; int n16 = 0, fx = -1, fphi = -1, fdcf = -1, fsidx = -1;
    for (int i = 0; i < n_in; ++i) {
        const int s = in_sizes[i];
        if (s == 12288) fx = i;
        else if (s == 96) fphi = i;
        else if (s == 8192) fdcf = i;
        else if (s == 16384) { if (n16 < 2) f16[n16] = i; ++n16; }
        else if (s == 32 || s == 64) fsidx = i;
    }
    if (fx >= 0 && fphi >= 0 && fdcf >= 0 && fsidx >= 0 && n16 == 2) {
        ix = fx; iphi = fphi; idcf = fdcf; isidx = fsidx;
        i16a = f16[0]; i16b = f16[1];
    }

    const float* x    = (const float*)d_in[ix];
    const float* cA   = (const float*)d_in[i16a];
    const float* cB   = (const float*)d_in[i16b];
    const float* phi  = (const float*)d_in[iphi];
    const float* dcf  = (const float*)d_in[idcf];
    const int*   sidx = (const int*)d_in[isidx];

    int*   flag = (int*)d_ws;                     // 256-B slot
    short* sp   = (short*)((char*)d_ws + 256);    // [12][4096] bf16 = 98304 B

    prep_pack<<<24, 256, 0, stream>>>(x, cA, cB, flag, sp);
    nudft_all8<<<NRK / 16, 512, 0, stream>>>(sp, cA, cB, flag, phi, dcf, sidx,
                                             (float*)d_out);
}